// Round 16
// baseline (141.100 us; speedup 1.0000x reference)
//
#include <hip/hip_runtime.h>

// ---------------------------------------------------------------------------
// Fused attention block for MI355X (gfx950) — round 16 = r15 champion +
// XCD-chunked swizzle on BOTH GEMM grids (attn swizzle validated r15: -1.2us).
// GEMM1: logical=(id&7)*32+(id>>3) -> each XCD owns 2 m-panels (1MB A,
// 16x reuse, L2-resident) x all n. GEMM2: logical=(id&7)*64+(id>>3) ->
// 4 m-panels (1MB A) + all B (2MB) = 3MB < 4MB L2 per XCD.
// Mechanism: GEMM1 is latency-bound (hbm 5.7%, Mfma 16%); converting the
// drain-blocking misses to L2 hits (~200cy vs 500-900) shortens the per-
// K-step stall that scheduling surgery (r12/r14) failed to remove.
//
// MFMA f32_16x16x32_f16 layout (HW-verified r1/r2):
//   A-frag: lane l holds A[row=l&15][k=8*(l>>4)+j]
//   B-frag: lane l holds B[k=8*(l>>4)+j][col=l&15]
//   C/D  : lane l reg r -> D[row=4*(l>>4)+r][col=l&15]
// sigma(R) = (R>>5)*32 + ((R>>2)&3)*8 + ((R>>4)&1)*4 + (R&3) folds P into
// B-frag layout in attn (r6, verified).
// ---------------------------------------------------------------------------

typedef _Float16 f16;
typedef _Float16 f16x8 __attribute__((ext_vector_type(8)));
typedef _Float16 f16x4 __attribute__((ext_vector_type(4)));
typedef float    f32x4 __attribute__((ext_vector_type(4)));

#define MFMA16(a, b, c) __builtin_amdgcn_mfma_f32_16x16x32_f16((a), (b), (c), 0, 0, 0)

__device__ __forceinline__ void gload16(const void* g, void* l) {
  __builtin_amdgcn_global_load_lds(
      (const __attribute__((address_space(1))) void*)g,
      (__attribute__((address_space(3))) void*)l, 16, 0, 0);
}

__device__ __forceinline__ float exp2_fast(float x) {
#if __has_builtin(__builtin_amdgcn_exp2f)
  return __builtin_amdgcn_exp2f(x);
#else
  float r;
  asm("v_exp_f32 %0, %1" : "=v"(r) : "v"(x));
  return r;
#endif
}
__device__ __forceinline__ unsigned pkrtz(float a, float b) {
  typedef __fp16 hf16x2 __attribute__((ext_vector_type(2)));
  union { hf16x2 h; unsigned u; } c;
  c.h = __builtin_amdgcn_cvt_pkrtz(a, b);
  return c.u;
}

// ---------------------------------------------------------------------------
// Helper kernels
// ---------------------------------------------------------------------------
__global__ void rope_table_kernel(const float* __restrict__ freqs, float* __restrict__ tbl) {
  int i = blockIdx.x * 256 + threadIdx.x;  // 2048*32
  if (i >= 2048 * 32) return;
  int s = i >> 5, j = i & 31;
  float f = freqs[i];
  tbl[s * 64 + j]      = cosf(f);
  tbl[s * 64 + 32 + j] = sinf(f);
}

__global__ void cast_f16_kernel(const float* __restrict__ in, f16* __restrict__ out, int n8) {
  int i = blockIdx.x * 256 + threadIdx.x;
  if (i >= n8) return;
  float4 a = ((const float4*)in)[2 * i];
  float4 b = ((const float4*)in)[2 * i + 1];
  f16x8 o;
  o[0] = (f16)a.x; o[1] = (f16)a.y; o[2] = (f16)a.z; o[3] = (f16)a.w;
  o[4] = (f16)b.x; o[5] = (f16)b.y; o[6] = (f16)b.z; o[7] = (f16)b.w;
  ((f16x8*)out)[i] = o;
}

__global__ void transpose_cast_kernel(const float* __restrict__ in, f16* __restrict__ out,
                                      int R, int C) {
  __shared__ float t[64][65];
  int c0 = blockIdx.x * 64, r0 = blockIdx.y * 64;
  int tx = threadIdx.x & 15, ty = threadIdx.x >> 4;
#pragma unroll
  for (int i = 0; i < 4; ++i) {
    float4 v = *(const float4*)&in[(size_t)(r0 + ty + 16 * i) * C + c0 + tx * 4];
    t[ty + 16 * i][tx * 4 + 0] = v.x;
    t[ty + 16 * i][tx * 4 + 1] = v.y;
    t[ty + 16 * i][tx * 4 + 2] = v.z;
    t[ty + 16 * i][tx * 4 + 3] = v.w;
  }
  __syncthreads();
#pragma unroll
  for (int i = 0; i < 4; ++i) {
    int n = c0 + ty + 16 * i;
    int k = r0 + tx * 4;
    f16x4 o;
    o[0] = (f16)t[tx * 4 + 0][ty + 16 * i];
    o[1] = (f16)t[tx * 4 + 1][ty + 16 * i];
    o[2] = (f16)t[tx * 4 + 2][ty + 16 * i];
    o[3] = (f16)t[tx * 4 + 3][ty + 16 * i];
    *(f16x4*)&out[(size_t)n * R + k] = o;
  }
}

__global__ void fill_debug_kernel(float* out, int n) {
  int i = blockIdx.x * 256 + threadIdx.x;
  if (i < n) out[i] = 12345.0f;
}

// ---------------------------------------------------------------------------
// GEMM1: 256^2 tile, 512 thr (8 waves, 2Mx4N; per-wave 128x64).
// dbuf 128KB LDS, stage(t+1) before compute(t), ONE barrier/K-step.
// XCD-chunked grid remap: each XCD owns 2 complete m-panels x all n.
// ---------------------------------------------------------------------------
__global__ __launch_bounds__(512, 1) void gemm_qkv_256(
    const f16* __restrict__ A, const f16* __restrict__ B, int K,
    f16* __restrict__ qraw, f16* __restrict__ kraw,
    f16* __restrict__ g16, f16* __restrict__ v_t) {
  __shared__ f16 sA[2][256 * 64], sB[2][256 * 64];
  const int tid = threadIdx.x, lane = tid & 63;
  const int wave = tid >> 6;            // 0..7
  const int wm = wave >> 2, wn = wave & 3;
  const int lg = lane >> 4, lr = lane & 15;
  const int id = blockIdx.y * 16 + blockIdx.x;      // hw linear order
  const int logical = (id & 7) * 32 + (id >> 3);    // bijective (256 blocks)
  const int n0 = (logical & 15) * 256, m0 = (logical >> 4) * 256;

  auto stg = [&](int k0, int p) {
#pragma unroll
    for (int r = 0; r < 4; ++r) {
      int off = (tid + r * 512) * 16;               // covers 32KB
      int row = off >> 7;                           // 128B rows, 0..255
      int col = ((off & 127) ^ ((row & 7) << 4)) >> 1;
      gload16(A + (size_t)(m0 + row) * K + k0 + col, (char*)sA[p] + off);
      gload16(B + (size_t)(n0 + row) * K + k0 + col, (char*)sB[p] + off);
    }
  };

  f32x4 acc[8][4];
#pragma unroll
  for (int m = 0; m < 8; ++m)
#pragma unroll
    for (int n = 0; n < 4; ++n) acc[m][n] = (f32x4){0.f, 0.f, 0.f, 0.f};

  stg(0, 0);
  const int NT = K >> 6;
  int cur = 0;
  for (int t = 0; t < NT; ++t, cur ^= 1) {
    __syncthreads();                        // stage(t) visible; buf cur^1 free
    if (t + 1 < NT) stg((t + 1) << 6, cur ^ 1);
#pragma unroll
    for (int ks = 0; ks < 2; ++ks) {
      f16x8 bfr[4];
#pragma unroll
      for (int n = 0; n < 4; ++n) {
        int row = wn * 64 + n * 16 + lr;
        int boff = (row << 7) + (ks << 6) + (lg << 4);
        boff ^= (row & 7) << 4;
        bfr[n] = *(const f16x8*)((const char*)sB[cur] + boff);
      }
#pragma unroll
      for (int m = 0; m < 8; ++m) {
        int row = wm * 128 + m * 16 + lr;
        int aoff = (row << 7) + (ks << 6) + (lg << 4);
        aoff ^= (row & 7) << 4;
        f16x8 afr = *(const f16x8*)((const char*)sA[cur] + aoff);
#pragma unroll
        for (int n = 0; n < 4; ++n) acc[m][n] = MFMA16(afr, bfr[n], acc[m][n]);
      }
    }
  }

  const int region = n0 >> 10;  // 0:q 1:k 2:v 3:gate
  if (region == 2) {
#pragma unroll
    for (int m = 0; m < 8; ++m) {
      int row = m0 + wm * 128 + m * 16 + 4 * lg;
#pragma unroll
      for (int n = 0; n < 4; ++n) {
        int c = (n0 & 1023) + wn * 64 + n * 16 + lr;
        int hh = c >> 6, d = c & 63;
        int bb = row >> 11, s = row & 2047;
        f16x4 pv;
        pv[0] = (f16)acc[m][n][0];
        pv[1] = (f16)acc[m][n][1];
        pv[2] = (f16)acc[m][n][2];
        pv[3] = (f16)acc[m][n][3];
        *(f16x4*)&v_t[(size_t)((bb * 16 + hh) * 64 + d) * 2048 + s] = pv;
      }
    }
  } else if (region == 3) {
#pragma unroll
    for (int m = 0; m < 8; ++m) {
      int row = m0 + wm * 128 + m * 16 + 4 * lg;
#pragma unroll
      for (int n = 0; n < 4; ++n) {
        int col = (n0 & 1023) + wn * 64 + n * 16 + lr;
#pragma unroll
        for (int r = 0; r < 4; ++r) {
          float sg = 1.0f / (1.0f + exp2_fast(acc[m][n][r] * -1.44269504f));
          g16[(size_t)(row + r) * 1024 + col] = (f16)sg;
        }
      }
    }
  } else {  // q (0) or k (1): raw f16
    f16* dst = region ? kraw : qraw;
#pragma unroll
    for (int m = 0; m < 8; ++m) {
      int row = m0 + wm * 128 + m * 16 + 4 * lg;
#pragma unroll
      for (int n = 0; n < 4; ++n) {
        int col = (n0 & 1023) + wn * 64 + n * 16 + lr;
#pragma unroll
        for (int r = 0; r < 4; ++r)
          dst[(size_t)(row + r) * 1024 + col] = (f16)acc[m][n][r];
      }
    }
  }
}

// ---------------------------------------------------------------------------
// GEMM2: 128x64 tile, dbuf 48KB, 2 blocks/CU. XCD-chunked remap: each XCD
// owns 4 m-panels (1MB A) + all B (2MB) = 3MB, fits 4MB L2.
// ---------------------------------------------------------------------------
__global__ __launch_bounds__(256, 2) void gemm_out_128x64(
    const f16* __restrict__ A, const f16* __restrict__ B,
    float* __restrict__ Cout, int M, int N, int K) {
  __shared__ f16 sA[2][128 * 64], sB[2][64 * 64];
  const int tid = threadIdx.x, lane = tid & 63;
  const int wave = tid >> 6, wm = wave >> 1, wn = wave & 1;
  const int lg = lane >> 4, lr = lane & 15;
  const int id = blockIdx.y * 16 + blockIdx.x;      // hw linear order (512)
  const int logical = (id & 7) * 64 + (id >> 3);    // bijective (512 blocks)
  const int n0 = (logical & 15) * 64, m0 = (logical >> 4) * 128;

  auto stg = [&](int k0, int p) {
#pragma unroll
    for (int r = 0; r < 4; ++r) {  // A: 16KB
      int off = (tid + r * 256) * 16;
      int row = off >> 7;
      int col = ((off & 127) ^ ((row & 7) << 4)) >> 1;
      gload16(A + (size_t)(m0 + row) * K + k0 + col, (char*)sA[p] + off);
    }
#pragma unroll
    for (int r = 0; r < 2; ++r) {  // B: 8KB
      int off = (tid + r * 256) * 16;
      int row = off >> 7;          // 0..63
      int col = ((off & 127) ^ ((row & 7) << 4)) >> 1;
      gload16(B + (size_t)(n0 + row) * K + k0 + col, (char*)sB[p] + off);
    }
  };

  f32x4 acc[4][2];
#pragma unroll
  for (int m = 0; m < 4; ++m)
#pragma unroll
    for (int n = 0; n < 2; ++n) acc[m][n] = (f32x4){0.f, 0.f, 0.f, 0.f};

  stg(0, 0);
  const int NT = K >> 6;
  int cur = 0;
  for (int t = 0; t < NT; ++t, cur ^= 1) {
    __syncthreads();
    if (t + 1 < NT) stg((t + 1) << 6, cur ^ 1);
#pragma unroll
    for (int ks = 0; ks < 2; ++ks) {
      f16x8 bfr[2];
#pragma unroll
      for (int n = 0; n < 2; ++n) {
        int row = wn * 32 + n * 16 + lr;
        int boff = (row << 7) + (ks << 6) + (lg << 4);
        boff ^= (row & 7) << 4;
        bfr[n] = *(const f16x8*)((const char*)sB[cur] + boff);
      }
#pragma unroll
      for (int m = 0; m < 4; ++m) {
        int row = wm * 64 + m * 16 + lr;
        int aoff = (row << 7) + (ks << 6) + (lg << 4);
        aoff ^= (row & 7) << 4;
        f16x8 afr = *(const f16x8*)((const char*)sA[cur] + aoff);
#pragma unroll
        for (int n = 0; n < 2; ++n) acc[m][n] = MFMA16(afr, bfr[n], acc[m][n]);
      }
    }
  }

#pragma unroll
  for (int m = 0; m < 4; ++m) {
    int row = m0 + wm * 64 + m * 16 + 4 * lg;
#pragma unroll
    for (int n = 0; n < 2; ++n) {
      int col = n0 + wn * 32 + n * 16 + lr;
#pragma unroll
      for (int r = 0; r < 4; ++r) Cout[(size_t)(row + r) * N + col] = acc[m][n][r];
    }
  }
}

// ---------------------------------------------------------------------------
// K-only LayerNorm + RoPE (r13, verified).
// ---------------------------------------------------------------------------
__global__ void norm_k16_kernel(const f16* __restrict__ kr, const float* __restrict__ tbl,
                                const float* __restrict__ kn_w, const float* __restrict__ kn_b,
                                f16* __restrict__ k_h) {
  int row = blockIdx.x;
  int s = row & 2047;
  int hh = threadIdx.x >> 4, sub = threadIdx.x & 15;
  int base = row * 1024 + hh * 64 + sub * 4;
  float c0 = tbl[s * 64 + sub * 2 + 0], c1 = tbl[s * 64 + sub * 2 + 1];
  float s0 = tbl[s * 64 + 32 + sub * 2 + 0], s1 = tbl[s * 64 + 32 + sub * 2 + 1];
  f16x4 xr = *(const f16x4*)&kr[base];
  float x0 = (float)xr[0], x1 = (float)xr[1], x2 = (float)xr[2], x3 = (float)xr[3];
  float sum = x0 + x1 + x2 + x3;
  sum += __shfl_xor(sum, 1); sum += __shfl_xor(sum, 2);
  sum += __shfl_xor(sum, 4); sum += __shfl_xor(sum, 8);
  float mu = sum * (1.0f / 64.0f);
  float d0 = x0 - mu, d1 = x1 - mu, d2 = x2 - mu, d3 = x3 - mu;
  float sq = d0 * d0 + d1 * d1 + d2 * d2 + d3 * d3;
  sq += __shfl_xor(sq, 1); sq += __shfl_xor(sq, 2);
  sq += __shfl_xor(sq, 4); sq += __shfl_xor(sq, 8);
  float rstd = rsqrtf(sq * (1.0f / 64.0f) + 1e-5f);
  float4 w = *(const float4*)&kn_w[sub * 4];
  float4 bb = *(const float4*)&kn_b[sub * 4];
  float n0 = d0 * rstd * w.x + bb.x;
  float n1 = d1 * rstd * w.y + bb.y;
  float n2 = d2 * rstd * w.z + bb.z;
  float n3 = d3 * rstd * w.w + bb.w;
  float r0 = n0 * c0 - n1 * s0, r1 = n0 * s0 + n1 * c0;
  float r2 = n2 * c1 - n3 * s1, r3 = n2 * s1 + n3 * c1;
  f16x4 ov;
  ov[0] = (f16)r0; ov[1] = (f16)r1; ov[2] = (f16)r2; ov[3] = (f16)r3;
  *(f16x4*)&k_h[base] = ov;
}

// ---------------------------------------------------------------------------
// Flash attention + fused Q LN+RoPE prologue + XCD-chunked swizzle (r15).
// ---------------------------------------------------------------------------
__global__ __launch_bounds__(256, 2) void attn_kernel(const f16* __restrict__ qraw,
                                                      const f16* __restrict__ k_h,
                                                      const f16* __restrict__ v_t,
                                                      const float* __restrict__ tbl,
                                                      const float* __restrict__ qn_w,
                                                      const float* __restrict__ qn_b,
                                                      const f16* __restrict__ g16,
                                                      f16* __restrict__ a16) {
  __shared__ __align__(16) char smem[65536];
  const int tid = threadIdx.x, lane = tid & 63, wave = tid >> 6;
  const int lg = lane >> 4, lr = lane & 15;
  const int id = blockIdx.x;
  const int logical = (id & 7) * 64 + (id >> 3);  // XCD-chunked remap
  const int bh = logical >> 4, qt = logical & 15;
  const int b = bh >> 4, h = bh & 15;
  const int qrow0 = b * 2048 + qt * 128 + wave * 32;

  auto stage = [&](int kv0, int p) {
    char* kb = smem + p * 16384;
    char* vb = smem + 32768 + p * 16384;
#pragma unroll
    for (int r = 0; r < 4; ++r) {
      int off = (tid + r * 256) * 16;
      {
        int row = off >> 7;
        int col = ((off & 127) ^ ((row & 7) << 4)) >> 1;
        int g = ((row >> 5) << 5) + (((row >> 2) & 3) << 3) + (((row >> 4) & 1) << 2) + (row & 3);
        gload16(&k_h[(size_t)(b * 2048 + kv0 + g) * 1024 + h * 64 + col], kb + off);
      }
      {
        int d = off >> 8;
        int col = ((off & 255) ^ ((d & 15) << 4)) >> 1;
        gload16(&v_t[(size_t)(bh * 64 + d) * 2048 + kv0 + col], vb + off);
      }
    }
  };

  stage(0, 0);  // prologue prefetch (overlaps Q LN below)

  // ---- fused Q LN + RoPE ----
  float wv[16], bv[16];
#pragma unroll
  for (int ks = 0; ks < 2; ++ks) {
    float4 wa = *(const float4*)&qn_w[ks * 32 + lg * 8];
    float4 wb = *(const float4*)&qn_w[ks * 32 + lg * 8 + 4];
    float4 ba = *(const float4*)&qn_b[ks * 32 + lg * 8];
    float4 bbv = *(const float4*)&qn_b[ks * 32 + lg * 8 + 4];
    wv[ks * 8 + 0] = wa.x; wv[ks * 8 + 1] = wa.y; wv[ks * 8 + 2] = wa.z; wv[ks * 8 + 3] = wa.w;
    wv[ks * 8 + 4] = wb.x; wv[ks * 8 + 5] = wb.y; wv[ks * 8 + 6] = wb.z; wv[ks * 8 + 7] = wb.w;
    bv[ks * 8 + 0] = ba.x; bv[ks * 8 + 1] = ba.y; bv[ks * 8 + 2] = ba.z; bv[ks * 8 + 3] = ba.w;
    bv[ks * 8 + 4] = bbv.x; bv[ks * 8 + 5] = bbv.y; bv[ks * 8 + 6] = bbv.z; bv[ks * 8 + 7] = bbv.w;
  }

  f16x8 qf[2][2];
#pragma unroll
  for (int n = 0; n < 2; ++n) {
    int row = qrow0 + n * 16 + lr;
    f16x8 raw[2];
    raw[0] = *(const f16x8*)&qraw[(size_t)row * 1024 + h * 64 + lg * 8];
    raw[1] = *(const f16x8*)&qraw[(size_t)row * 1024 + h * 64 + 32 + lg * 8];
    float x[16];
#pragma unroll
    for (int ks = 0; ks < 2; ++ks)
#pragma unroll
      for (int j = 0; j < 8; ++j) x[ks * 8 + j] = (float)raw[ks][j];
    float sum = 0.f;
#pragma unroll
    for (int i = 0; i < 16; ++i) sum += x[i];
    sum += __shfl_xor(sum, 16);
    sum += __shfl_xor(sum, 32);
    float mu = sum * (1.0f / 64.0f);
    float sq = 0.f;
#pragma unroll
    for (int i = 0; i < 16; ++i) { float d = x[i] - mu; sq += d * d; }
    sq += __shfl_xor(sq, 16);
    sq += __shfl_xor(sq, 32);
    float rstd = rsqrtf(sq * (1.0f / 64.0f) + 1e-5f);
    int srow = row & 2047;
    const float* tb = tbl + srow * 64;
#pragma unroll
    for (int ks = 0; ks < 2; ++ks) {
      float4 c4 = *(const float4*)&tb[ks * 16 + lg * 4];
      float4 s4 = *(const float4*)&tb[32 + ks * 16 + lg * 4];
      float cc[4] = {c4.x, c4.y, c4.z, c4.w};
      float ss[4] = {s4.x, s4.y, s4.z, s4.w};
      f16x8 o;
#pragma unroll
      for (int jj = 0; jj < 4; ++jj) {
        float y0 = (x[ks * 8 + 2 * jj] - mu) * rstd * wv[ks * 8 + 2 * jj] + bv[ks * 8 + 2 * jj];
        float y1 = (x[ks * 8 + 2 * jj + 1] - mu) * rstd * wv[ks * 8 + 2 * jj + 1] + bv[ks * 8 + 2 * jj + 1];
        o[2 * jj]     = (f16)(y0 * cc[jj] - y1 * ss[jj]);
        o[2 * jj + 1] = (f16)(y0 * ss[jj] + y1 * cc[jj]);
      }
      qf[n][ks] = o;
    }
  }

  f16x8 ones;
#pragma unroll
  for (int j = 0; j < 8; ++j) ones[j] = (f16)1.0f;

  f32x4 accO[4][2];
#pragma unroll
  for (int m = 0; m < 4; ++m) {
    accO[m][0] = (f32x4){0.f, 0.f, 0.f, 0.f};
    accO[m][1] = (f32x4){0.f, 0.f, 0.f, 0.f};
  }
  f32x4 accL[2] = {(f32x4){0.f, 0.f, 0.f, 0.f}, (f32x4){0.f, 0.f, 0.f, 0.f}};
  float mrun[2] = {-1e30f, -1e30f};
  const float SCL2 = 0.125f * 1.44269504f;  // scale * log2(e)
  const float THRP = 44.36f;                // 8 / SCL2
  const f32x4 fz = (f32x4){0.f, 0.f, 0.f, 0.f};

  int cur = 0;
  for (int t = 0; t < 16; ++t, cur ^= 1) {
    __syncthreads();                            // stage(t) landed
    if (t < 15) stage((t + 1) * 128, cur ^ 1);  // prefetch under compute(t)

    const char* kb = smem + cur * 16384;
    const char* vb = smem + 32768 + cur * 16384;

    // ---- QK^T: st = K~.Q^T (zero-C init) ----
    f32x4 st[8][2];
    __builtin_amdgcn_s_setprio(1);
#pragma unroll
    for (int m = 0; m < 8; ++m) {
      int row = m * 16 + lr;
      int koff0 = ((row << 7) + (lg << 4)) ^ ((row & 7) << 4);
      int koff1 = ((row << 7) + 64 + (lg << 4)) ^ ((row & 7) << 4);
      f16x8 a0 = *(const f16x8*)(kb + koff0);
      f16x8 a1 = *(const f16x8*)(kb + koff1);
      st[m][0] = MFMA16(a1, qf[0][1], MFMA16(a0, qf[0][0], fz));
      st[m][1] = MFMA16(a1, qf[1][1], MFMA16(a0, qf[1][0], fz));
    }
    __builtin_amdgcn_s_setprio(0);

    // ---- softmax + P pack (registers only) ----
    uint2 pdw[2][8];
#pragma unroll
    for (int n = 0; n < 2; ++n) {
      float t03 = fmaxf(fmaxf(fmaxf(st[0][n][0], st[0][n][1]), fmaxf(st[0][n][2], st[0][n][3])),
                        fmaxf(fmaxf(st[1][n][0], st[1][n][1]), fmaxf(st[1][n][2], st[1][n][3])));
      float t47 = fmaxf(fmaxf(fmaxf(st[2][n][0], st[2][n][1]), fmaxf(st[2][n][2], st[2][n][3])),
                        fmaxf(fmaxf(st[3][n][0], st[3][n][1]), fmaxf(st[3][n][2], st[3][n][3])));
      float t8b = fmaxf(fmaxf(fmaxf(st[4][n][0], st[4][n][1]), fmaxf(st[4][n][2], st[4][n][3])),
                        fmaxf(fmaxf(st[5][n][0], st[5][n][1]), fmaxf(st[5][n][2], st[5][n][3])));
      float tcf = fmaxf(fmaxf(fmaxf(st[6][n][0], st[6][n][1]), fmaxf(st[6][n][2], st[6][n][3])),
                        fmaxf(fmaxf(st[7][n][0], st[7][n][1]), fmaxf(st[7][n][2], st[7][n][3])));
      float vm = fmaxf(fmaxf(t03, t47), fmaxf(t8b, tcf));
      vm = fmaxf(vm, __shfl_xor(vm, 16));
      vm = fmaxf(vm, __shfl_xor(vm, 32));
      if (__any(vm > mrun[n] + THRP)) {  // defer-max with threshold
        float mnew = fmaxf(mrun[n], vm);
        float fac = exp2_fast((mrun[n] - mnew) * SCL2);
        mrun[n] = mnew;
        accL[n] *= fac;
#pragma unroll
        for (int m = 0; m < 4; ++m) accO[m][n] *= fac;
      }
      float mc = mrun[n] * SCL2;
#pragma unroll
      for (int m = 0; m < 8; ++m) {
        float p0 = exp2_fast(st[m][n][0] * SCL2 - mc);
        float p1 = exp2_fast(st[m][n][1] * SCL2 - mc);
        float p2 = exp2_fast(st[m][n][2] * SCL2 - mc);
        float p3 = exp2_fast(st[m][n][3] * SCL2 - mc);
        pdw[n][m].x = pkrtz(p0, p1);
        pdw[n][m].y = pkrtz(p2, p3);
      }
    }

    // ---- PV: P already in B-frag layout thanks to sigma ----
    f16x8 pb[2][4];
#pragma unroll
    for (int n = 0; n < 2; ++n)
#pragma unroll
      for (int ks = 0; ks < 4; ++ks) {
        union { uint4 u; f16x8 h; } c;
        c.u = make_uint4(pdw[n][2 * ks].x, pdw[n][2 * ks].y,
                         pdw[n][2 * ks + 1].x, pdw[n][2 * ks + 1].y);
        pb[n][ks] = c.h;
      }
    __builtin_amdgcn_s_setprio(1);
#pragma unroll
    for (int m = 0; m < 4; ++m)
#pragma unroll
      for (int ks = 0; ks < 4; ++ks) {
        int d = m * 16 + lr;
        int voff = (d << 8) + (ks << 6) + (lg << 4);
        voff ^= (d & 15) << 4;
        f16x8 av = *(const f16x8*)(vb + voff);
        accO[m][0] = MFMA16(av, pb[0][ks], accO[m][0]);
        accO[m][1] = MFMA16(av, pb[1][ks], accO[m][1]);
      }
#pragma unroll
    for (int ks = 0; ks < 4; ++ks) {
      accL[0] = MFMA16(ones, pb[0][ks], accL[0]);
      accL[1] = MFMA16(ones, pb[1][ks], accL[1]);
    }
    __builtin_amdgcn_s_setprio(0);
  }

  // ---- epilogue: normalize, gate (pre-sigmoided f16), write fp16 ----
#pragma unroll
  for (int n = 0; n < 2; ++n) {
    float rl = 1.0f / accL[n][0];
    int orow = qrow0 + n * 16 + lr;
#pragma unroll
    for (int m = 0; m < 4; ++m) {
      size_t idx = (size_t)orow * 1024 + h * 64 + m * 16 + lg * 4;
      f16x4 gv = *(const f16x4*)&g16[idx];
      f16x4 ov;
      ov[0] = (f16)(accO[m][n][0] * rl * (float)gv[0]);
      ov[1] = (f16)(accO[m][n][1] * rl * (float)gv[1]);
      ov[2] = (f16)(accO[m][n][2] * rl * (float)gv[2]);
      ov[3] = (f16)(accO[m][n][3] * rl * (float)gv[3]);
      *(f16x4*)&a16[idx] = ov;
    }
  }
}

// ---------------------------------------------------------------------------
extern "C" void kernel_launch(void* const* d_in, const int* in_sizes, int n_in,
                              void* d_out, int out_size, void* d_ws, size_t ws_size,
                              hipStream_t stream) {
  const float* x      = (const float*)d_in[0];
  const float* freqs  = (const float*)d_in[1];
  const float* w_qkv  = (const float*)d_in[2];
  const float* w_out  = (const float*)d_in[3];
  const float* qn_w   = (const float*)d_in[4];
  const float* qn_b   = (const float*)d_in[5];
  const float* kn_w   = (const float*)d_in[6];
  const float* kn_b   = (const float*)d_in[7];
  float* out = (float*)d_out;
  char* ws = (char*)d_ws;
  const size_t MB = 1024 * 1024;
  // ws map (~67 MB):
  f16*   v_t   = (f16*)(ws + 0);         // 8 MB  [b,h,d,s]
  f16*   x16   = (f16*)(ws + 8 * MB);    // 8 MB  (aliased by a16 after GEMM1)
  f16*   wq16  = (f16*)(ws + 16 * MB);   // 8 MB  w_qkv^T fp16
  f16*   wo16  = (f16*)(ws + 24 * MB);   // 2 MB  w_out^T fp16
  f16*   qraw  = (f16*)(ws + 26 * MB);   // 8 MB  raw q (LN fused in attn)
  f16*   kraw  = (f16*)(ws + 34 * MB);   // 8 MB  raw k (pre-LN)
  f16*   k_h   = (f16*)(ws + 50 * MB);   // 8 MB
  f16*   g16   = (f16*)(ws + 58 * MB);   // 8 MB  sigmoid(gate) f16
  float* tbl   = (float*)(ws + 66 * MB); // 0.5 MB
  f16*   a16   = x16;                    // alias: x dead after GEMM1

  if (ws_size < (size_t)67 * MB) {  // sentinel: signals ws shortfall in absmax
    fill_debug_kernel<<<(out_size + 255) / 256, 256, 0, stream>>>(out, out_size);
    return;
  }

  rope_table_kernel<<<256, 256, 0, stream>>>(freqs, tbl);
  cast_f16_kernel<<<2048, 256, 0, stream>>>(x, x16, 524288);
  transpose_cast_kernel<<<dim3(64, 16), 256, 0, stream>>>(w_qkv, wq16, 1024, 4096);
  transpose_cast_kernel<<<dim3(16, 16), 256, 0, stream>>>(w_out, wo16, 1024, 1024);

  gemm_qkv_256<<<dim3(16, 16), 512, 0, stream>>>(x16, wq16, 1024, qraw, kraw, g16, v_t);
  norm_k16_kernel<<<4096, 256, 0, stream>>>(kraw, tbl, kn_w, kn_b, k_h);
  attn_kernel<<<512, 256, 0, stream>>>(qraw, k_h, v_t, tbl, qn_w, qn_b, g16, a16);
  gemm_out_128x64<<<dim3(16, 32), 256, 0, stream>>>(a16, wo16, out, 4096, 1024, 1024);
}

// Round 18
// 140.821 us; speedup vs baseline: 1.0020x; 1.0020x over previous
//
#include <hip/hip_runtime.h>

// ---------------------------------------------------------------------------
// Fused attention block for MI355X (gfx950) — round 18 = r15 champion
// restored verbatim (140.5us, verified). r17's 4-block/CU attn restructure
// failed the post-timing re-validation (suspected replay-visible race,
// unresolved analytically) — reverted.
// Final structure: cast/transpose -> GEMM1 256^2 depth-2 dbuf (epilogue
// scatters raw-f16 q/k, sigmoid-f16 gate, V^T f16) -> K-only LN+RoPE ->
// flash attention (fused Q LN+RoPE prologue, sigma-permuted K rows keep P
// register-resident, dbuf stage-ahead, 1 barrier/tile, XCD-chunked swizzle)
// -> GEMM2 128x64 -> f32 out.
//
// MFMA f32_16x16x32_f16 layout (HW-verified r1/r2):
//   A-frag: lane l holds A[row=l&15][k=8*(l>>4)+j]
//   B-frag: lane l holds B[k=8*(l>>4)+j][col=l&15]
//   C/D  : lane l reg r -> D[row=4*(l>>4)+r][col=l&15]
// sigma(R) = (R>>5)*32 + ((R>>2)&3)*8 + ((R>>4)&1)*4 + (R&3) folds P into
// B-frag layout in attn (r6, verified).
// ---------------------------------------------------------------------------

typedef _Float16 f16;
typedef _Float16 f16x8 __attribute__((ext_vector_type(8)));
typedef _Float16 f16x4 __attribute__((ext_vector_type(4)));
typedef float    f32x4 __attribute__((ext_vector_type(4)));

#define MFMA16(a, b, c) __builtin_amdgcn_mfma_f32_16x16x32_f16((a), (b), (c), 0, 0, 0)

__device__ __forceinline__ void gload16(const void* g, void* l) {
  __builtin_amdgcn_global_load_lds(
      (const __attribute__((address_space(1))) void*)g,
      (__attribute__((address_space(3))) void*)l, 16, 0, 0);
}

__device__ __forceinline__ float exp2_fast(float x) {
#if __has_builtin(__builtin_amdgcn_exp2f)
  return __builtin_amdgcn_exp2f(x);
#else
  float r;
  asm("v_exp_f32 %0, %1" : "=v"(r) : "v"(x));
  return r;
#endif
}
__device__ __forceinline__ unsigned pkrtz(float a, float b) {
  typedef __fp16 hf16x2 __attribute__((ext_vector_type(2)));
  union { hf16x2 h; unsigned u; } c;
  c.h = __builtin_amdgcn_cvt_pkrtz(a, b);
  return c.u;
}

// ---------------------------------------------------------------------------
// Helper kernels
// ---------------------------------------------------------------------------
__global__ void rope_table_kernel(const float* __restrict__ freqs, float* __restrict__ tbl) {
  int i = blockIdx.x * 256 + threadIdx.x;  // 2048*32
  if (i >= 2048 * 32) return;
  int s = i >> 5, j = i & 31;
  float f = freqs[i];
  tbl[s * 64 + j]      = cosf(f);
  tbl[s * 64 + 32 + j] = sinf(f);
}

__global__ void cast_f16_kernel(const float* __restrict__ in, f16* __restrict__ out, int n8) {
  int i = blockIdx.x * 256 + threadIdx.x;
  if (i >= n8) return;
  float4 a = ((const float4*)in)[2 * i];
  float4 b = ((const float4*)in)[2 * i + 1];
  f16x8 o;
  o[0] = (f16)a.x; o[1] = (f16)a.y; o[2] = (f16)a.z; o[3] = (f16)a.w;
  o[4] = (f16)b.x; o[5] = (f16)b.y; o[6] = (f16)b.z; o[7] = (f16)b.w;
  ((f16x8*)out)[i] = o;
}

__global__ void transpose_cast_kernel(const float* __restrict__ in, f16* __restrict__ out,
                                      int R, int C) {
  __shared__ float t[64][65];
  int c0 = blockIdx.x * 64, r0 = blockIdx.y * 64;
  int tx = threadIdx.x & 15, ty = threadIdx.x >> 4;
#pragma unroll
  for (int i = 0; i < 4; ++i) {
    float4 v = *(const float4*)&in[(size_t)(r0 + ty + 16 * i) * C + c0 + tx * 4];
    t[ty + 16 * i][tx * 4 + 0] = v.x;
    t[ty + 16 * i][tx * 4 + 1] = v.y;
    t[ty + 16 * i][tx * 4 + 2] = v.z;
    t[ty + 16 * i][tx * 4 + 3] = v.w;
  }
  __syncthreads();
#pragma unroll
  for (int i = 0; i < 4; ++i) {
    int n = c0 + ty + 16 * i;
    int k = r0 + tx * 4;
    f16x4 o;
    o[0] = (f16)t[tx * 4 + 0][ty + 16 * i];
    o[1] = (f16)t[tx * 4 + 1][ty + 16 * i];
    o[2] = (f16)t[tx * 4 + 2][ty + 16 * i];
    o[3] = (f16)t[tx * 4 + 3][ty + 16 * i];
    *(f16x4*)&out[(size_t)n * R + k] = o;
  }
}

__global__ void fill_debug_kernel(float* out, int n) {
  int i = blockIdx.x * 256 + threadIdx.x;
  if (i < n) out[i] = 12345.0f;
}

// ---------------------------------------------------------------------------
// GEMM1: 256^2 tile, 512 thr (8 waves, 2Mx4N; per-wave 128x64).
// dbuf 128KB LDS, stage(t+1) before compute(t), ONE barrier/K-step. (r11)
// ---------------------------------------------------------------------------
__global__ __launch_bounds__(512, 1) void gemm_qkv_256(
    const f16* __restrict__ A, const f16* __restrict__ B, int K,
    f16* __restrict__ qraw, f16* __restrict__ kraw,
    f16* __restrict__ g16, f16* __restrict__ v_t) {
  __shared__ f16 sA[2][256 * 64], sB[2][256 * 64];
  const int tid = threadIdx.x, lane = tid & 63;
  const int wave = tid >> 6;            // 0..7
  const int wm = wave >> 2, wn = wave & 3;
  const int lg = lane >> 4, lr = lane & 15;
  const int n0 = blockIdx.x * 256, m0 = blockIdx.y * 256;

  auto stg = [&](int k0, int p) {
#pragma unroll
    for (int r = 0; r < 4; ++r) {
      int off = (tid + r * 512) * 16;               // covers 32KB
      int row = off >> 7;                           // 128B rows, 0..255
      int col = ((off & 127) ^ ((row & 7) << 4)) >> 1;
      gload16(A + (size_t)(m0 + row) * K + k0 + col, (char*)sA[p] + off);
      gload16(B + (size_t)(n0 + row) * K + k0 + col, (char*)sB[p] + off);
    }
  };

  f32x4 acc[8][4];
#pragma unroll
  for (int m = 0; m < 8; ++m)
#pragma unroll
    for (int n = 0; n < 4; ++n) acc[m][n] = (f32x4){0.f, 0.f, 0.f, 0.f};

  stg(0, 0);
  const int NT = K >> 6;
  int cur = 0;
  for (int t = 0; t < NT; ++t, cur ^= 1) {
    __syncthreads();                        // stage(t) visible; buf cur^1 free
    if (t + 1 < NT) stg((t + 1) << 6, cur ^ 1);
#pragma unroll
    for (int ks = 0; ks < 2; ++ks) {
      f16x8 bfr[4];
#pragma unroll
      for (int n = 0; n < 4; ++n) {
        int row = wn * 64 + n * 16 + lr;
        int boff = (row << 7) + (ks << 6) + (lg << 4);
        boff ^= (row & 7) << 4;
        bfr[n] = *(const f16x8*)((const char*)sB[cur] + boff);
      }
#pragma unroll
      for (int m = 0; m < 8; ++m) {
        int row = wm * 128 + m * 16 + lr;
        int aoff = (row << 7) + (ks << 6) + (lg << 4);
        aoff ^= (row & 7) << 4;
        f16x8 afr = *(const f16x8*)((const char*)sA[cur] + aoff);
#pragma unroll
        for (int n = 0; n < 4; ++n) acc[m][n] = MFMA16(afr, bfr[n], acc[m][n]);
      }
    }
  }

  const int region = n0 >> 10;  // 0:q 1:k 2:v 3:gate
  if (region == 2) {
#pragma unroll
    for (int m = 0; m < 8; ++m) {
      int row = m0 + wm * 128 + m * 16 + 4 * lg;
#pragma unroll
      for (int n = 0; n < 4; ++n) {
        int c = (n0 & 1023) + wn * 64 + n * 16 + lr;
        int hh = c >> 6, d = c & 63;
        int bb = row >> 11, s = row & 2047;
        f16x4 pv;
        pv[0] = (f16)acc[m][n][0];
        pv[1] = (f16)acc[m][n][1];
        pv[2] = (f16)acc[m][n][2];
        pv[3] = (f16)acc[m][n][3];
        *(f16x4*)&v_t[(size_t)((bb * 16 + hh) * 64 + d) * 2048 + s] = pv;
      }
    }
  } else if (region == 3) {
#pragma unroll
    for (int m = 0; m < 8; ++m) {
      int row = m0 + wm * 128 + m * 16 + 4 * lg;
#pragma unroll
      for (int n = 0; n < 4; ++n) {
        int col = (n0 & 1023) + wn * 64 + n * 16 + lr;
#pragma unroll
        for (int r = 0; r < 4; ++r) {
          float sg = 1.0f / (1.0f + exp2_fast(acc[m][n][r] * -1.44269504f));
          g16[(size_t)(row + r) * 1024 + col] = (f16)sg;
        }
      }
    }
  } else {  // q (0) or k (1): raw f16
    f16* dst = region ? kraw : qraw;
#pragma unroll
    for (int m = 0; m < 8; ++m) {
      int row = m0 + wm * 128 + m * 16 + 4 * lg;
#pragma unroll
      for (int n = 0; n < 4; ++n) {
        int col = (n0 & 1023) + wn * 64 + n * 16 + lr;
#pragma unroll
        for (int r = 0; r < 4; ++r)
          dst[(size_t)(row + r) * 1024 + col] = (f16)acc[m][n][r];
      }
    }
  }
}

// ---------------------------------------------------------------------------
// GEMM2: 128x64 tile (r13). dbuf 48KB, 2 blocks/CU.
// ---------------------------------------------------------------------------
__global__ __launch_bounds__(256, 2) void gemm_out_128x64(
    const f16* __restrict__ A, const f16* __restrict__ B,
    float* __restrict__ Cout, int M, int N, int K) {
  __shared__ f16 sA[2][128 * 64], sB[2][64 * 64];
  const int tid = threadIdx.x, lane = tid & 63;
  const int wave = tid >> 6, wm = wave >> 1, wn = wave & 1;
  const int lg = lane >> 4, lr = lane & 15;
  const int n0 = blockIdx.x * 64, m0 = blockIdx.y * 128;

  auto stg = [&](int k0, int p) {
#pragma unroll
    for (int r = 0; r < 4; ++r) {  // A: 16KB
      int off = (tid + r * 256) * 16;
      int row = off >> 7;
      int col = ((off & 127) ^ ((row & 7) << 4)) >> 1;
      gload16(A + (size_t)(m0 + row) * K + k0 + col, (char*)sA[p] + off);
    }
#pragma unroll
    for (int r = 0; r < 2; ++r) {  // B: 8KB
      int off = (tid + r * 256) * 16;
      int row = off >> 7;          // 0..63
      int col = ((off & 127) ^ ((row & 7) << 4)) >> 1;
      gload16(B + (size_t)(n0 + row) * K + k0 + col, (char*)sB[p] + off);
    }
  };

  f32x4 acc[4][2];
#pragma unroll
  for (int m = 0; m < 4; ++m)
#pragma unroll
    for (int n = 0; n < 2; ++n) acc[m][n] = (f32x4){0.f, 0.f, 0.f, 0.f};

  stg(0, 0);
  const int NT = K >> 6;
  int cur = 0;
  for (int t = 0; t < NT; ++t, cur ^= 1) {
    __syncthreads();
    if (t + 1 < NT) stg((t + 1) << 6, cur ^ 1);
#pragma unroll
    for (int ks = 0; ks < 2; ++ks) {
      f16x8 bfr[2];
#pragma unroll
      for (int n = 0; n < 2; ++n) {
        int row = wn * 32 + n * 16 + lr;
        int boff = (row << 7) + (ks << 6) + (lg << 4);
        boff ^= (row & 7) << 4;
        bfr[n] = *(const f16x8*)((const char*)sB[cur] + boff);
      }
#pragma unroll
      for (int m = 0; m < 4; ++m) {
        int row = wm * 64 + m * 16 + lr;
        int aoff = (row << 7) + (ks << 6) + (lg << 4);
        aoff ^= (row & 7) << 4;
        f16x8 afr = *(const f16x8*)((const char*)sA[cur] + aoff);
#pragma unroll
        for (int n = 0; n < 2; ++n) acc[m][n] = MFMA16(afr, bfr[n], acc[m][n]);
      }
    }
  }

#pragma unroll
  for (int m = 0; m < 4; ++m) {
    int row = m0 + wm * 64 + m * 16 + 4 * lg;
#pragma unroll
    for (int n = 0; n < 2; ++n) {
      int col = n0 + wn * 32 + n * 16 + lr;
#pragma unroll
      for (int r = 0; r < 4; ++r) Cout[(size_t)(row + r) * N + col] = acc[m][n][r];
    }
  }
}

// ---------------------------------------------------------------------------
// K-only LayerNorm + RoPE (r13, verified).
// ---------------------------------------------------------------------------
__global__ void norm_k16_kernel(const f16* __restrict__ kr, const float* __restrict__ tbl,
                                const float* __restrict__ kn_w, const float* __restrict__ kn_b,
                                f16* __restrict__ k_h) {
  int row = blockIdx.x;
  int s = row & 2047;
  int hh = threadIdx.x >> 4, sub = threadIdx.x & 15;
  int base = row * 1024 + hh * 64 + sub * 4;
  float c0 = tbl[s * 64 + sub * 2 + 0], c1 = tbl[s * 64 + sub * 2 + 1];
  float s0 = tbl[s * 64 + 32 + sub * 2 + 0], s1 = tbl[s * 64 + 32 + sub * 2 + 1];
  f16x4 xr = *(const f16x4*)&kr[base];
  float x0 = (float)xr[0], x1 = (float)xr[1], x2 = (float)xr[2], x3 = (float)xr[3];
  float sum = x0 + x1 + x2 + x3;
  sum += __shfl_xor(sum, 1); sum += __shfl_xor(sum, 2);
  sum += __shfl_xor(sum, 4); sum += __shfl_xor(sum, 8);
  float mu = sum * (1.0f / 64.0f);
  float d0 = x0 - mu, d1 = x1 - mu, d2 = x2 - mu, d3 = x3 - mu;
  float sq = d0 * d0 + d1 * d1 + d2 * d2 + d3 * d3;
  sq += __shfl_xor(sq, 1); sq += __shfl_xor(sq, 2);
  sq += __shfl_xor(sq, 4); sq += __shfl_xor(sq, 8);
  float rstd = rsqrtf(sq * (1.0f / 64.0f) + 1e-5f);
  float4 w = *(const float4*)&kn_w[sub * 4];
  float4 bb = *(const float4*)&kn_b[sub * 4];
  float n0 = d0 * rstd * w.x + bb.x;
  float n1 = d1 * rstd * w.y + bb.y;
  float n2 = d2 * rstd * w.z + bb.z;
  float n3 = d3 * rstd * w.w + bb.w;
  float r0 = n0 * c0 - n1 * s0, r1 = n0 * s0 + n1 * c0;
  float r2 = n2 * c1 - n3 * s1, r3 = n2 * s1 + n3 * c1;
  f16x4 ov;
  ov[0] = (f16)r0; ov[1] = (f16)r1; ov[2] = (f16)r2; ov[3] = (f16)r3;
  *(f16x4*)&k_h[base] = ov;
}

// ---------------------------------------------------------------------------
// Flash attention + fused Q LN+RoPE prologue + XCD-chunked swizzle:
// logical = (id&7)*64 + (id>>3) — bijective (512 blocks), so XCD i
// (= hw id % 8) owns logical blocks 64i..64i+63 = heads 4i..4i+3 entirely;
// per-XCD K/V working set = 2MB, fits the 4MB L2. (r15, verified)
// ---------------------------------------------------------------------------
__global__ __launch_bounds__(256, 2) void attn_kernel(const f16* __restrict__ qraw,
                                                      const f16* __restrict__ k_h,
                                                      const f16* __restrict__ v_t,
                                                      const float* __restrict__ tbl,
                                                      const float* __restrict__ qn_w,
                                                      const float* __restrict__ qn_b,
                                                      const f16* __restrict__ g16,
                                                      f16* __restrict__ a16) {
  __shared__ __align__(16) char smem[65536];
  const int tid = threadIdx.x, lane = tid & 63, wave = tid >> 6;
  const int lg = lane >> 4, lr = lane & 15;
  const int id = blockIdx.x;
  const int logical = (id & 7) * 64 + (id >> 3);  // XCD-chunked remap
  const int bh = logical >> 4, qt = logical & 15;
  const int b = bh >> 4, h = bh & 15;
  const int qrow0 = b * 2048 + qt * 128 + wave * 32;

  auto stage = [&](int kv0, int p) {
    char* kb = smem + p * 16384;
    char* vb = smem + 32768 + p * 16384;
#pragma unroll
    for (int r = 0; r < 4; ++r) {
      int off = (tid + r * 256) * 16;
      {
        int row = off >> 7;
        int col = ((off & 127) ^ ((row & 7) << 4)) >> 1;
        int g = ((row >> 5) << 5) + (((row >> 2) & 3) << 3) + (((row >> 4) & 1) << 2) + (row & 3);
        gload16(&k_h[(size_t)(b * 2048 + kv0 + g) * 1024 + h * 64 + col], kb + off);
      }
      {
        int d = off >> 8;
        int col = ((off & 255) ^ ((d & 15) << 4)) >> 1;
        gload16(&v_t[(size_t)(bh * 64 + d) * 2048 + kv0 + col], vb + off);
      }
    }
  };

  stage(0, 0);  // prologue prefetch (overlaps Q LN below)

  // ---- fused Q LN + RoPE ----
  float wv[16], bv[16];
#pragma unroll
  for (int ks = 0; ks < 2; ++ks) {
    float4 wa = *(const float4*)&qn_w[ks * 32 + lg * 8];
    float4 wb = *(const float4*)&qn_w[ks * 32 + lg * 8 + 4];
    float4 ba = *(const float4*)&qn_b[ks * 32 + lg * 8];
    float4 bbv = *(const float4*)&qn_b[ks * 32 + lg * 8 + 4];
    wv[ks * 8 + 0] = wa.x; wv[ks * 8 + 1] = wa.y; wv[ks * 8 + 2] = wa.z; wv[ks * 8 + 3] = wa.w;
    wv[ks * 8 + 4] = wb.x; wv[ks * 8 + 5] = wb.y; wv[ks * 8 + 6] = wb.z; wv[ks * 8 + 7] = wb.w;
    bv[ks * 8 + 0] = ba.x; bv[ks * 8 + 1] = ba.y; bv[ks * 8 + 2] = ba.z; bv[ks * 8 + 3] = ba.w;
    bv[ks * 8 + 4] = bbv.x; bv[ks * 8 + 5] = bbv.y; bv[ks * 8 + 6] = bbv.z; bv[ks * 8 + 7] = bbv.w;
  }

  f16x8 qf[2][2];
#pragma unroll
  for (int n = 0; n < 2; ++n) {
    int row = qrow0 + n * 16 + lr;
    f16x8 raw[2];
    raw[0] = *(const f16x8*)&qraw[(size_t)row * 1024 + h * 64 + lg * 8];
    raw[1] = *(const f16x8*)&qraw[(size_t)row * 1024 + h * 64 + 32 + lg * 8];
    float x[16];
#pragma unroll
    for (int ks = 0; ks < 2; ++ks)
#pragma unroll
      for (int j = 0; j < 8; ++j) x[ks * 8 + j] = (float)raw[ks][j];
    float sum = 0.f;
#pragma unroll
    for (int i = 0; i < 16; ++i) sum += x[i];
    sum += __shfl_xor(sum, 16);
    sum += __shfl_xor(sum, 32);
    float mu = sum * (1.0f / 64.0f);
    float sq = 0.f;
#pragma unroll
    for (int i = 0; i < 16; ++i) { float d = x[i] - mu; sq += d * d; }
    sq += __shfl_xor(sq, 16);
    sq += __shfl_xor(sq, 32);
    float rstd = rsqrtf(sq * (1.0f / 64.0f) + 1e-5f);
    int srow = row & 2047;
    const float* tb = tbl + srow * 64;
#pragma unroll
    for (int ks = 0; ks < 2; ++ks) {
      float4 c4 = *(const float4*)&tb[ks * 16 + lg * 4];
      float4 s4 = *(const float4*)&tb[32 + ks * 16 + lg * 4];
      float cc[4] = {c4.x, c4.y, c4.z, c4.w};
      float ss[4] = {s4.x, s4.y, s4.z, s4.w};
      f16x8 o;
#pragma unroll
      for (int jj = 0; jj < 4; ++jj) {
        float y0 = (x[ks * 8 + 2 * jj] - mu) * rstd * wv[ks * 8 + 2 * jj] + bv[ks * 8 + 2 * jj];
        float y1 = (x[ks * 8 + 2 * jj + 1] - mu) * rstd * wv[ks * 8 + 2 * jj + 1] + bv[ks * 8 + 2 * jj + 1];
        o[2 * jj]     = (f16)(y0 * cc[jj] - y1 * ss[jj]);
        o[2 * jj + 1] = (f16)(y0 * ss[jj] + y1 * cc[jj]);
      }
      qf[n][ks] = o;
    }
  }

  f16x8 ones;
#pragma unroll
  for (int j = 0; j < 8; ++j) ones[j] = (f16)1.0f;

  f32x4 accO[4][2];
#pragma unroll
  for (int m = 0; m < 4; ++m) {
    accO[m][0] = (f32x4){0.f, 0.f, 0.f, 0.f};
    accO[m][1] = (f32x4){0.f, 0.f, 0.f, 0.f};
  }
  f32x4 accL[2] = {(f32x4){0.f, 0.f, 0.f, 0.f}, (f32x4){0.f, 0.f, 0.f, 0.f}};
  float mrun[2] = {-1e30f, -1e30f};
  const float SCL2 = 0.125f * 1.44269504f;  // scale * log2(e)
  const float THRP = 44.36f;                // 8 / SCL2
  const f32x4 fz = (f32x4){0.f, 0.f, 0.f, 0.f};

  int cur = 0;
  for (int t = 0; t < 16; ++t, cur ^= 1) {
    __syncthreads();                            // stage(t) landed
    if (t < 15) stage((t + 1) * 128, cur ^ 1);  // prefetch under compute(t)

    const char* kb = smem + cur * 16384;
    const char* vb = smem + 32768 + cur * 16384;

    // ---- QK^T: st = K~.Q^T (zero-C init) ----
    f32x4 st[8][2];
    __builtin_amdgcn_s_setprio(1);
#pragma unroll
    for (int m = 0; m < 8; ++m) {
      int row = m * 16 + lr;
      int koff0 = ((row << 7) + (lg << 4)) ^ ((row & 7) << 4);
      int koff1 = ((row << 7) + 64 + (lg << 4)) ^ ((row & 7) << 4);
      f16x8 a0 = *(const f16x8*)(kb + koff0);
      f16x8 a1 = *(const f16x8*)(kb + koff1);
      st[m][0] = MFMA16(a1, qf[0][1], MFMA16(a0, qf[0][0], fz));
      st[m][1] = MFMA16(a1, qf[1][1], MFMA16(a0, qf[1][0], fz));
    }
    __builtin_amdgcn_s_setprio(0);

    // ---- softmax + P pack (registers only) ----
    uint2 pdw[2][8];
#pragma unroll
    for (int n = 0; n < 2; ++n) {
      float t03 = fmaxf(fmaxf(fmaxf(st[0][n][0], st[0][n][1]), fmaxf(st[0][n][2], st[0][n][3])),
                        fmaxf(fmaxf(st[1][n][0], st[1][n][1]), fmaxf(st[1][n][2], st[1][n][3])));
      float t47 = fmaxf(fmaxf(fmaxf(st[2][n][0], st[2][n][1]), fmaxf(st[2][n][2], st[2][n][3])),
                        fmaxf(fmaxf(st[3][n][0], st[3][n][1]), fmaxf(st[3][n][2], st[3][n][3])));
      float t8b = fmaxf(fmaxf(fmaxf(st[4][n][0], st[4][n][1]), fmaxf(st[4][n][2], st[4][n][3])),
                        fmaxf(fmaxf(st[5][n][0], st[5][n][1]), fmaxf(st[5][n][2], st[5][n][3])));
      float tcf = fmaxf(fmaxf(fmaxf(st[6][n][0], st[6][n][1]), fmaxf(st[6][n][2], st[6][n][3])),
                        fmaxf(fmaxf(st[7][n][0], st[7][n][1]), fmaxf(st[7][n][2], st[7][n][3])));
      float vm = fmaxf(fmaxf(t03, t47), fmaxf(t8b, tcf));
      vm = fmaxf(vm, __shfl_xor(vm, 16));
      vm = fmaxf(vm, __shfl_xor(vm, 32));
      if (__any(vm > mrun[n] + THRP)) {  // defer-max with threshold
        float mnew = fmaxf(mrun[n], vm);
        float fac = exp2_fast((mrun[n] - mnew) * SCL2);
        mrun[n] = mnew;
        accL[n] *= fac;
#pragma unroll
        for (int m = 0; m < 4; ++m) accO[m][n] *= fac;
      }
      float mc = mrun[n] * SCL2;
#pragma unroll
      for (int m = 0; m < 8; ++m) {
        float p0 = exp2_fast(st[m][n][0] * SCL2 - mc);
        float p1 = exp2_fast(st[m][n][1] * SCL2 - mc);
        float p2 = exp2_fast(st[m][n][2] * SCL2 - mc);
        float p3 = exp2_fast(st[m][n][3] * SCL2 - mc);
        pdw[n][m].x = pkrtz(p0, p1);
        pdw[n][m].y = pkrtz(p2, p3);
      }
    }

    // ---- PV: P already in B-frag layout thanks to sigma ----
    f16x8 pb[2][4];
#pragma unroll
    for (int n = 0; n < 2; ++n)
#pragma unroll
      for (int ks = 0; ks < 4; ++ks) {
        union { uint4 u; f16x8 h; } c;
        c.u = make_uint4(pdw[n][2 * ks].x, pdw[n][2 * ks].y,
                         pdw[n][2 * ks + 1].x, pdw[n][2 * ks + 1].y);
        pb[n][ks] = c.h;
      }
    __builtin_amdgcn_s_setprio(1);
#pragma unroll
    for (int m = 0; m < 4; ++m)
#pragma unroll
      for (int ks = 0; ks < 4; ++ks) {
        int d = m * 16 + lr;
        int voff = (d << 8) + (ks << 6) + (lg << 4);
        voff ^= (d & 15) << 4;
        f16x8 av = *(const f16x8*)(vb + voff);
        accO[m][0] = MFMA16(av, pb[0][ks], accO[m][0]);
        accO[m][1] = MFMA16(av, pb[1][ks], accO[m][1]);
      }
#pragma unroll
    for (int ks = 0; ks < 4; ++ks) {
      accL[0] = MFMA16(ones, pb[0][ks], accL[0]);
      accL[1] = MFMA16(ones, pb[1][ks], accL[1]);
    }
    __builtin_amdgcn_s_setprio(0);
  }

  // ---- epilogue: normalize, gate (pre-sigmoided f16), write fp16 ----
#pragma unroll
  for (int n = 0; n < 2; ++n) {
    float rl = 1.0f / accL[n][0];
    int orow = qrow0 + n * 16 + lr;
#pragma unroll
    for (int m = 0; m < 4; ++m) {
      size_t idx = (size_t)orow * 1024 + h * 64 + m * 16 + lg * 4;
      f16x4 gv = *(const f16x4*)&g16[idx];
      f16x4 ov;
      ov[0] = (f16)(accO[m][n][0] * rl * (float)gv[0]);
      ov[1] = (f16)(accO[m][n][1] * rl * (float)gv[1]);
      ov[2] = (f16)(accO[m][n][2] * rl * (float)gv[2]);
      ov[3] = (f16)(accO[m][n][3] * rl * (float)gv[3]);
      *(f16x4*)&a16[idx] = ov;
    }
  }
}

// ---------------------------------------------------------------------------
extern "C" void kernel_launch(void* const* d_in, const int* in_sizes, int n_in,
                              void* d_out, int out_size, void* d_ws, size_t ws_size,
                              hipStream_t stream) {
  const float* x      = (const float*)d_in[0];
  const float* freqs  = (const float*)d_in[1];
  const float* w_qkv  = (const float*)d_in[2];
  const float* w_out  = (const float*)d_in[3];
  const float* qn_w   = (const float*)d_in[4];
  const float* qn_b   = (const float*)d_in[5];
  const float* kn_w   = (const float*)d_in[6];
  const float* kn_b   = (const float*)d_in[7];
  float* out = (float*)d_out;
  char* ws = (char*)d_ws;
  const size_t MB = 1024 * 1024;
  // ws map (~67 MB):
  f16*   v_t   = (f16*)(ws + 0);         // 8 MB  [b,h,d,s]
  f16*   x16   = (f16*)(ws + 8 * MB);    // 8 MB  (aliased by a16 after GEMM1)
  f16*   wq16  = (f16*)(ws + 16 * MB);   // 8 MB  w_qkv^T fp16
  f16*   wo16  = (f16*)(ws + 24 * MB);   // 2 MB  w_out^T fp16
  f16*   qraw  = (f16*)(ws + 26 * MB);   // 8 MB  raw q (LN fused in attn)
  f16*   kraw  = (f16*)(ws + 34 * MB);   // 8 MB  raw k (pre-LN)
  f16*   k_h   = (f16*)(ws + 50 * MB);   // 8 MB
  f16*   g16   = (f16*)(ws + 58 * MB);   // 8 MB  sigmoid(gate) f16
  float* tbl   = (float*)(ws + 66 * MB); // 0.5 MB
  f16*   a16   = x16;                    // alias: x dead after GEMM1

  if (ws_size < (size_t)67 * MB) {  // sentinel: signals ws shortfall in absmax
    fill_debug_kernel<<<(out_size + 255) / 256, 256, 0, stream>>>(out, out_size);
    return;
  }

  rope_table_kernel<<<256, 256, 0, stream>>>(freqs, tbl);
  cast_f16_kernel<<<2048, 256, 0, stream>>>(x, x16, 524288);
  transpose_cast_kernel<<<dim3(64, 16), 256, 0, stream>>>(w_qkv, wq16, 1024, 4096);
  transpose_cast_kernel<<<dim3(16, 16), 256, 0, stream>>>(w_out, wo16, 1024, 1024);

  gemm_qkv_256<<<dim3(16, 16), 512, 0, stream>>>(x16, wq16, 1024, qraw, kraw, g16, v_t);
  norm_k16_kernel<<<4096, 256, 0, stream>>>(kraw, tbl, kn_w, kn_b, k_h);
  attn_kernel<<<512, 256, 0, stream>>>(qraw, k_h, v_t, tbl, qn_w, qn_b, g16, a16);
  gemm_out_128x64<<<dim3(16, 32), 256, 0, stream>>>(a16, wo16, out, 4096, 1024, 1024);
}

// Round 19
// 131.888 us; speedup vs baseline: 1.0698x; 1.0677x over previous
//
#include <hip/hip_runtime.h>

// ---------------------------------------------------------------------------
// Fused attention block for MI355X (gfx950) — round 19 = r18 champion +
// single fused prep kernel (rope_table + cast + 2x transpose in ONE launch;
// each was a tiny under-saturating memory-bound kernel with launch gaps).
// Per-branch code identical to the verified r18 helpers -> outputs
// bit-identical. Everything else = r18 (140.8us, verified).
//
// MFMA f32_16x16x32_f16 layout (HW-verified r1/r2):
//   A-frag: lane l holds A[row=l&15][k=8*(l>>4)+j]
//   B-frag: lane l holds B[k=8*(l>>4)+j][col=l&15]
//   C/D  : lane l reg r -> D[row=4*(l>>4)+r][col=l&15]
// sigma(R) = (R>>5)*32 + ((R>>2)&3)*8 + ((R>>4)&1)*4 + (R&3) folds P into
// B-frag layout in attn (r6, verified).
// ---------------------------------------------------------------------------

typedef _Float16 f16;
typedef _Float16 f16x8 __attribute__((ext_vector_type(8)));
typedef _Float16 f16x4 __attribute__((ext_vector_type(4)));
typedef float    f32x4 __attribute__((ext_vector_type(4)));

#define MFMA16(a, b, c) __builtin_amdgcn_mfma_f32_16x16x32_f16((a), (b), (c), 0, 0, 0)

__device__ __forceinline__ void gload16(const void* g, void* l) {
  __builtin_amdgcn_global_load_lds(
      (const __attribute__((address_space(1))) void*)g,
      (__attribute__((address_space(3))) void*)l, 16, 0, 0);
}

__device__ __forceinline__ float exp2_fast(float x) {
#if __has_builtin(__builtin_amdgcn_exp2f)
  return __builtin_amdgcn_exp2f(x);
#else
  float r;
  asm("v_exp_f32 %0, %1" : "=v"(r) : "v"(x));
  return r;
#endif
}
__device__ __forceinline__ unsigned pkrtz(float a, float b) {
  typedef __fp16 hf16x2 __attribute__((ext_vector_type(2)));
  union { hf16x2 h; unsigned u; } c;
  c.h = __builtin_amdgcn_cvt_pkrtz(a, b);
  return c.u;
}

// ---------------------------------------------------------------------------
// Fused prep kernel: blocks [0,256) rope table; [256,2304) cast x->f16;
// [2304,3328) transpose w_qkv (64x16 tile-grid); [3328,3584) transpose w_out.
// Bodies identical to r18's separate kernels.
// ---------------------------------------------------------------------------
__device__ __forceinline__ void transpose_body(const float* __restrict__ in,
                                               f16* __restrict__ out, int R, int C,
                                               int bx, int by, float (*t)[65]) {
  int c0 = bx * 64, r0 = by * 64;
  int tx = threadIdx.x & 15, ty = threadIdx.x >> 4;
#pragma unroll
  for (int i = 0; i < 4; ++i) {
    float4 v = *(const float4*)&in[(size_t)(r0 + ty + 16 * i) * C + c0 + tx * 4];
    t[ty + 16 * i][tx * 4 + 0] = v.x;
    t[ty + 16 * i][tx * 4 + 1] = v.y;
    t[ty + 16 * i][tx * 4 + 2] = v.z;
    t[ty + 16 * i][tx * 4 + 3] = v.w;
  }
  __syncthreads();
#pragma unroll
  for (int i = 0; i < 4; ++i) {
    int n = c0 + ty + 16 * i;
    int k = r0 + tx * 4;
    f16x4 o;
    o[0] = (f16)t[tx * 4 + 0][ty + 16 * i];
    o[1] = (f16)t[tx * 4 + 1][ty + 16 * i];
    o[2] = (f16)t[tx * 4 + 2][ty + 16 * i];
    o[3] = (f16)t[tx * 4 + 3][ty + 16 * i];
    *(f16x4*)&out[(size_t)n * R + k] = o;
  }
}

__global__ __launch_bounds__(256) void prep_kernel(
    const float* __restrict__ freqs, float* __restrict__ tbl,
    const float* __restrict__ x, f16* __restrict__ x16,
    const float* __restrict__ w_qkv, f16* __restrict__ wq16,
    const float* __restrict__ w_out, f16* __restrict__ wo16) {
  __shared__ float t[64][65];
  const int blk = blockIdx.x;
  if (blk < 256) {  // rope table: 2048*32 entries
    int i = blk * 256 + threadIdx.x;
    int s = i >> 5, j = i & 31;
    float f = freqs[i];
    tbl[s * 64 + j]      = cosf(f);
    tbl[s * 64 + 32 + j] = sinf(f);
  } else if (blk < 2304) {  // cast x -> f16, 524288 chunks of 8
    int i = (blk - 256) * 256 + threadIdx.x;
    float4 a = ((const float4*)x)[2 * i];
    float4 b = ((const float4*)x)[2 * i + 1];
    f16x8 o;
    o[0] = (f16)a.x; o[1] = (f16)a.y; o[2] = (f16)a.z; o[3] = (f16)a.w;
    o[4] = (f16)b.x; o[5] = (f16)b.y; o[6] = (f16)b.z; o[7] = (f16)b.w;
    ((f16x8*)x16)[i] = o;
  } else if (blk < 3328) {  // transpose w_qkv [1024][4096] -> [4096][1024]
    int id2 = blk - 2304;
    transpose_body(w_qkv, wq16, 1024, 4096, id2 & 63, id2 >> 6, t);
  } else {  // transpose w_out [1024][1024] -> [1024][1024]
    int id3 = blk - 3328;
    transpose_body(w_out, wo16, 1024, 1024, id3 & 15, id3 >> 4, t);
  }
}

__global__ void fill_debug_kernel(float* out, int n) {
  int i = blockIdx.x * 256 + threadIdx.x;
  if (i < n) out[i] = 12345.0f;
}

// ---------------------------------------------------------------------------
// GEMM1: 256^2 tile, 512 thr (8 waves, 2Mx4N; per-wave 128x64).
// dbuf 128KB LDS, stage(t+1) before compute(t), ONE barrier/K-step. (r11)
// ---------------------------------------------------------------------------
__global__ __launch_bounds__(512, 1) void gemm_qkv_256(
    const f16* __restrict__ A, const f16* __restrict__ B, int K,
    f16* __restrict__ qraw, f16* __restrict__ kraw,
    f16* __restrict__ g16, f16* __restrict__ v_t) {
  __shared__ f16 sA[2][256 * 64], sB[2][256 * 64];
  const int tid = threadIdx.x, lane = tid & 63;
  const int wave = tid >> 6;            // 0..7
  const int wm = wave >> 2, wn = wave & 3;
  const int lg = lane >> 4, lr = lane & 15;
  const int n0 = blockIdx.x * 256, m0 = blockIdx.y * 256;

  auto stg = [&](int k0, int p) {
#pragma unroll
    for (int r = 0; r < 4; ++r) {
      int off = (tid + r * 512) * 16;               // covers 32KB
      int row = off >> 7;                           // 128B rows, 0..255
      int col = ((off & 127) ^ ((row & 7) << 4)) >> 1;
      gload16(A + (size_t)(m0 + row) * K + k0 + col, (char*)sA[p] + off);
      gload16(B + (size_t)(n0 + row) * K + k0 + col, (char*)sB[p] + off);
    }
  };

  f32x4 acc[8][4];
#pragma unroll
  for (int m = 0; m < 8; ++m)
#pragma unroll
    for (int n = 0; n < 4; ++n) acc[m][n] = (f32x4){0.f, 0.f, 0.f, 0.f};

  stg(0, 0);
  const int NT = K >> 6;
  int cur = 0;
  for (int t = 0; t < NT; ++t, cur ^= 1) {
    __syncthreads();                        // stage(t) visible; buf cur^1 free
    if (t + 1 < NT) stg((t + 1) << 6, cur ^ 1);
#pragma unroll
    for (int ks = 0; ks < 2; ++ks) {
      f16x8 bfr[4];
#pragma unroll
      for (int n = 0; n < 4; ++n) {
        int row = wn * 64 + n * 16 + lr;
        int boff = (row << 7) + (ks << 6) + (lg << 4);
        boff ^= (row & 7) << 4;
        bfr[n] = *(const f16x8*)((const char*)sB[cur] + boff);
      }
#pragma unroll
      for (int m = 0; m < 8; ++m) {
        int row = wm * 128 + m * 16 + lr;
        int aoff = (row << 7) + (ks << 6) + (lg << 4);
        aoff ^= (row & 7) << 4;
        f16x8 afr = *(const f16x8*)((const char*)sA[cur] + aoff);
#pragma unroll
        for (int n = 0; n < 4; ++n) acc[m][n] = MFMA16(afr, bfr[n], acc[m][n]);
      }
    }
  }

  const int region = n0 >> 10;  // 0:q 1:k 2:v 3:gate
  if (region == 2) {
#pragma unroll
    for (int m = 0; m < 8; ++m) {
      int row = m0 + wm * 128 + m * 16 + 4 * lg;
#pragma unroll
      for (int n = 0; n < 4; ++n) {
        int c = (n0 & 1023) + wn * 64 + n * 16 + lr;
        int hh = c >> 6, d = c & 63;
        int bb = row >> 11, s = row & 2047;
        f16x4 pv;
        pv[0] = (f16)acc[m][n][0];
        pv[1] = (f16)acc[m][n][1];
        pv[2] = (f16)acc[m][n][2];
        pv[3] = (f16)acc[m][n][3];
        *(f16x4*)&v_t[(size_t)((bb * 16 + hh) * 64 + d) * 2048 + s] = pv;
      }
    }
  } else if (region == 3) {
#pragma unroll
    for (int m = 0; m < 8; ++m) {
      int row = m0 + wm * 128 + m * 16 + 4 * lg;
#pragma unroll
      for (int n = 0; n < 4; ++n) {
        int col = (n0 & 1023) + wn * 64 + n * 16 + lr;
#pragma unroll
        for (int r = 0; r < 4; ++r) {
          float sg = 1.0f / (1.0f + exp2_fast(acc[m][n][r] * -1.44269504f));
          g16[(size_t)(row + r) * 1024 + col] = (f16)sg;
        }
      }
    }
  } else {  // q (0) or k (1): raw f16
    f16* dst = region ? kraw : qraw;
#pragma unroll
    for (int m = 0; m < 8; ++m) {
      int row = m0 + wm * 128 + m * 16 + 4 * lg;
#pragma unroll
      for (int n = 0; n < 4; ++n) {
        int col = (n0 & 1023) + wn * 64 + n * 16 + lr;
#pragma unroll
        for (int r = 0; r < 4; ++r)
          dst[(size_t)(row + r) * 1024 + col] = (f16)acc[m][n][r];
      }
    }
  }
}

// ---------------------------------------------------------------------------
// GEMM2: 128x64 tile (r13). dbuf 48KB, 2 blocks/CU.
// ---------------------------------------------------------------------------
__global__ __launch_bounds__(256, 2) void gemm_out_128x64(
    const f16* __restrict__ A, const f16* __restrict__ B,
    float* __restrict__ Cout, int M, int N, int K) {
  __shared__ f16 sA[2][128 * 64], sB[2][64 * 64];
  const int tid = threadIdx.x, lane = tid & 63;
  const int wave = tid >> 6, wm = wave >> 1, wn = wave & 1;
  const int lg = lane >> 4, lr = lane & 15;
  const int n0 = blockIdx.x * 64, m0 = blockIdx.y * 128;

  auto stg = [&](int k0, int p) {
#pragma unroll
    for (int r = 0; r < 4; ++r) {  // A: 16KB
      int off = (tid + r * 256) * 16;
      int row = off >> 7;
      int col = ((off & 127) ^ ((row & 7) << 4)) >> 1;
      gload16(A + (size_t)(m0 + row) * K + k0 + col, (char*)sA[p] + off);
    }
#pragma unroll
    for (int r = 0; r < 2; ++r) {  // B: 8KB
      int off = (tid + r * 256) * 16;
      int row = off >> 7;          // 0..63
      int col = ((off & 127) ^ ((row & 7) << 4)) >> 1;
      gload16(B + (size_t)(n0 + row) * K + k0 + col, (char*)sB[p] + off);
    }
  };

  f32x4 acc[4][2];
#pragma unroll
  for (int m = 0; m < 4; ++m)
#pragma unroll
    for (int n = 0; n < 2; ++n) acc[m][n] = (f32x4){0.f, 0.f, 0.f, 0.f};

  stg(0, 0);
  const int NT = K >> 6;
  int cur = 0;
  for (int t = 0; t < NT; ++t, cur ^= 1) {
    __syncthreads();
    if (t + 1 < NT) stg((t + 1) << 6, cur ^ 1);
#pragma unroll
    for (int ks = 0; ks < 2; ++ks) {
      f16x8 bfr[2];
#pragma unroll
      for (int n = 0; n < 2; ++n) {
        int row = wn * 32 + n * 16 + lr;
        int boff = (row << 7) + (ks << 6) + (lg << 4);
        boff ^= (row & 7) << 4;
        bfr[n] = *(const f16x8*)((const char*)sB[cur] + boff);
      }
#pragma unroll
      for (int m = 0; m < 4; ++m) {
        int row = wm * 64 + m * 16 + lr;
        int aoff = (row << 7) + (ks << 6) + (lg << 4);
        aoff ^= (row & 7) << 4;
        f16x8 afr = *(const f16x8*)((const char*)sA[cur] + aoff);
#pragma unroll
        for (int n = 0; n < 2; ++n) acc[m][n] = MFMA16(afr, bfr[n], acc[m][n]);
      }
    }
  }

#pragma unroll
  for (int m = 0; m < 4; ++m) {
    int row = m0 + wm * 64 + m * 16 + 4 * lg;
#pragma unroll
    for (int n = 0; n < 2; ++n) {
      int col = n0 + wn * 32 + n * 16 + lr;
#pragma unroll
      for (int r = 0; r < 4; ++r) Cout[(size_t)(row + r) * N + col] = acc[m][n][r];
    }
  }
}

// ---------------------------------------------------------------------------
// K-only LayerNorm + RoPE (r13, verified).
// ---------------------------------------------------------------------------
__global__ void norm_k16_kernel(const f16* __restrict__ kr, const float* __restrict__ tbl,
                                const float* __restrict__ kn_w, const float* __restrict__ kn_b,
                                f16* __restrict__ k_h) {
  int row = blockIdx.x;
  int s = row & 2047;
  int hh = threadIdx.x >> 4, sub = threadIdx.x & 15;
  int base = row * 1024 + hh * 64 + sub * 4;
  float c0 = tbl[s * 64 + sub * 2 + 0], c1 = tbl[s * 64 + sub * 2 + 1];
  float s0 = tbl[s * 64 + 32 + sub * 2 + 0], s1 = tbl[s * 64 + 32 + sub * 2 + 1];
  f16x4 xr = *(const f16x4*)&kr[base];
  float x0 = (float)xr[0], x1 = (float)xr[1], x2 = (float)xr[2], x3 = (float)xr[3];
  float sum = x0 + x1 + x2 + x3;
  sum += __shfl_xor(sum, 1); sum += __shfl_xor(sum, 2);
  sum += __shfl_xor(sum, 4); sum += __shfl_xor(sum, 8);
  float mu = sum * (1.0f / 64.0f);
  float d0 = x0 - mu, d1 = x1 - mu, d2 = x2 - mu, d3 = x3 - mu;
  float sq = d0 * d0 + d1 * d1 + d2 * d2 + d3 * d3;
  sq += __shfl_xor(sq, 1); sq += __shfl_xor(sq, 2);
  sq += __shfl_xor(sq, 4); sq += __shfl_xor(sq, 8);
  float rstd = rsqrtf(sq * (1.0f / 64.0f) + 1e-5f);
  float4 w = *(const float4*)&kn_w[sub * 4];
  float4 bb = *(const float4*)&kn_b[sub * 4];
  float n0 = d0 * rstd * w.x + bb.x;
  float n1 = d1 * rstd * w.y + bb.y;
  float n2 = d2 * rstd * w.z + bb.z;
  float n3 = d3 * rstd * w.w + bb.w;
  float r0 = n0 * c0 - n1 * s0, r1 = n0 * s0 + n1 * c0;
  float r2 = n2 * c1 - n3 * s1, r3 = n2 * s1 + n3 * c1;
  f16x4 ov;
  ov[0] = (f16)r0; ov[1] = (f16)r1; ov[2] = (f16)r2; ov[3] = (f16)r3;
  *(f16x4*)&k_h[base] = ov;
}

// ---------------------------------------------------------------------------
// Flash attention + fused Q LN+RoPE prologue + XCD-chunked swizzle (r15).
// ---------------------------------------------------------------------------
__global__ __launch_bounds__(256, 2) void attn_kernel(const f16* __restrict__ qraw,
                                                      const f16* __restrict__ k_h,
                                                      const f16* __restrict__ v_t,
                                                      const float* __restrict__ tbl,
                                                      const float* __restrict__ qn_w,
                                                      const float* __restrict__ qn_b,
                                                      const f16* __restrict__ g16,
                                                      f16* __restrict__ a16) {
  __shared__ __align__(16) char smem[65536];
  const int tid = threadIdx.x, lane = tid & 63, wave = tid >> 6;
  const int lg = lane >> 4, lr = lane & 15;
  const int id = blockIdx.x;
  const int logical = (id & 7) * 64 + (id >> 3);  // XCD-chunked remap
  const int bh = logical >> 4, qt = logical & 15;
  const int b = bh >> 4, h = bh & 15;
  const int qrow0 = b * 2048 + qt * 128 + wave * 32;

  auto stage = [&](int kv0, int p) {
    char* kb = smem + p * 16384;
    char* vb = smem + 32768 + p * 16384;
#pragma unroll
    for (int r = 0; r < 4; ++r) {
      int off = (tid + r * 256) * 16;
      {
        int row = off >> 7;
        int col = ((off & 127) ^ ((row & 7) << 4)) >> 1;
        int g = ((row >> 5) << 5) + (((row >> 2) & 3) << 3) + (((row >> 4) & 1) << 2) + (row & 3);
        gload16(&k_h[(size_t)(b * 2048 + kv0 + g) * 1024 + h * 64 + col], kb + off);
      }
      {
        int d = off >> 8;
        int col = ((off & 255) ^ ((d & 15) << 4)) >> 1;
        gload16(&v_t[(size_t)(bh * 64 + d) * 2048 + kv0 + col], vb + off);
      }
    }
  };

  stage(0, 0);  // prologue prefetch (overlaps Q LN below)

  // ---- fused Q LN + RoPE ----
  float wv[16], bv[16];
#pragma unroll
  for (int ks = 0; ks < 2; ++ks) {
    float4 wa = *(const float4*)&qn_w[ks * 32 + lg * 8];
    float4 wb = *(const float4*)&qn_w[ks * 32 + lg * 8 + 4];
    float4 ba = *(const float4*)&qn_b[ks * 32 + lg * 8];
    float4 bbv = *(const float4*)&qn_b[ks * 32 + lg * 8 + 4];
    wv[ks * 8 + 0] = wa.x; wv[ks * 8 + 1] = wa.y; wv[ks * 8 + 2] = wa.z; wv[ks * 8 + 3] = wa.w;
    wv[ks * 8 + 4] = wb.x; wv[ks * 8 + 5] = wb.y; wv[ks * 8 + 6] = wb.z; wv[ks * 8 + 7] = wb.w;
    bv[ks * 8 + 0] = ba.x; bv[ks * 8 + 1] = ba.y; bv[ks * 8 + 2] = ba.z; bv[ks * 8 + 3] = ba.w;
    bv[ks * 8 + 4] = bbv.x; bv[ks * 8 + 5] = bbv.y; bv[ks * 8 + 6] = bbv.z; bv[ks * 8 + 7] = bbv.w;
  }

  f16x8 qf[2][2];
#pragma unroll
  for (int n = 0; n < 2; ++n) {
    int row = qrow0 + n * 16 + lr;
    f16x8 raw[2];
    raw[0] = *(const f16x8*)&qraw[(size_t)row * 1024 + h * 64 + lg * 8];
    raw[1] = *(const f16x8*)&qraw[(size_t)row * 1024 + h * 64 + 32 + lg * 8];
    float x[16];
#pragma unroll
    for (int ks = 0; ks < 2; ++ks)
#pragma unroll
      for (int j = 0; j < 8; ++j) x[ks * 8 + j] = (float)raw[ks][j];
    float sum = 0.f;
#pragma unroll
    for (int i = 0; i < 16; ++i) sum += x[i];
    sum += __shfl_xor(sum, 16);
    sum += __shfl_xor(sum, 32);
    float mu = sum * (1.0f / 64.0f);
    float sq = 0.f;
#pragma unroll
    for (int i = 0; i < 16; ++i) { float d = x[i] - mu; sq += d * d; }
    sq += __shfl_xor(sq, 16);
    sq += __shfl_xor(sq, 32);
    float rstd = rsqrtf(sq * (1.0f / 64.0f) + 1e-5f);
    int srow = row & 2047;
    const float* tb = tbl + srow * 64;
#pragma unroll
    for (int ks = 0; ks < 2; ++ks) {
      float4 c4 = *(const float4*)&tb[ks * 16 + lg * 4];
      float4 s4 = *(const float4*)&tb[32 + ks * 16 + lg * 4];
      float cc[4] = {c4.x, c4.y, c4.z, c4.w};
      float ss[4] = {s4.x, s4.y, s4.z, s4.w};
      f16x8 o;
#pragma unroll
      for (int jj = 0; jj < 4; ++jj) {
        float y0 = (x[ks * 8 + 2 * jj] - mu) * rstd * wv[ks * 8 + 2 * jj] + bv[ks * 8 + 2 * jj];
        float y1 = (x[ks * 8 + 2 * jj + 1] - mu) * rstd * wv[ks * 8 + 2 * jj + 1] + bv[ks * 8 + 2 * jj + 1];
        o[2 * jj]     = (f16)(y0 * cc[jj] - y1 * ss[jj]);
        o[2 * jj + 1] = (f16)(y0 * ss[jj] + y1 * cc[jj]);
      }
      qf[n][ks] = o;
    }
  }

  f16x8 ones;
#pragma unroll
  for (int j = 0; j < 8; ++j) ones[j] = (f16)1.0f;

  f32x4 accO[4][2];
#pragma unroll
  for (int m = 0; m < 4; ++m) {
    accO[m][0] = (f32x4){0.f, 0.f, 0.f, 0.f};
    accO[m][1] = (f32x4){0.f, 0.f, 0.f, 0.f};
  }
  f32x4 accL[2] = {(f32x4){0.f, 0.f, 0.f, 0.f}, (f32x4){0.f, 0.f, 0.f, 0.f}};
  float mrun[2] = {-1e30f, -1e30f};
  const float SCL2 = 0.125f * 1.44269504f;  // scale * log2(e)
  const float THRP = 44.36f;                // 8 / SCL2
  const f32x4 fz = (f32x4){0.f, 0.f, 0.f, 0.f};

  int cur = 0;
  for (int t = 0; t < 16; ++t, cur ^= 1) {
    __syncthreads();                            // stage(t) landed
    if (t < 15) stage((t + 1) * 128, cur ^ 1);  // prefetch under compute(t)

    const char* kb = smem + cur * 16384;
    const char* vb = smem + 32768 + cur * 16384;

    // ---- QK^T: st = K~.Q^T (zero-C init) ----
    f32x4 st[8][2];
    __builtin_amdgcn_s_setprio(1);
#pragma unroll
    for (int m = 0; m < 8; ++m) {
      int row = m * 16 + lr;
      int koff0 = ((row << 7) + (lg << 4)) ^ ((row & 7) << 4);
      int koff1 = ((row << 7) + 64 + (lg << 4)) ^ ((row & 7) << 4);
      f16x8 a0 = *(const f16x8*)(kb + koff0);
      f16x8 a1 = *(const f16x8*)(kb + koff1);
      st[m][0] = MFMA16(a1, qf[0][1], MFMA16(a0, qf[0][0], fz));
      st[m][1] = MFMA16(a1, qf[1][1], MFMA16(a0, qf[1][0], fz));
    }
    __builtin_amdgcn_s_setprio(0);

    // ---- softmax + P pack (registers only) ----
    uint2 pdw[2][8];
#pragma unroll
    for (int n = 0; n < 2; ++n) {
      float t03 = fmaxf(fmaxf(fmaxf(st[0][n][0], st[0][n][1]), fmaxf(st[0][n][2], st[0][n][3])),
                        fmaxf(fmaxf(st[1][n][0], st[1][n][1]), fmaxf(st[1][n][2], st[1][n][3])));
      float t47 = fmaxf(fmaxf(fmaxf(st[2][n][0], st[2][n][1]), fmaxf(st[2][n][2], st[2][n][3])),
                        fmaxf(fmaxf(st[3][n][0], st[3][n][1]), fmaxf(st[3][n][2], st[3][n][3])));
      float t8b = fmaxf(fmaxf(fmaxf(st[4][n][0], st[4][n][1]), fmaxf(st[4][n][2], st[4][n][3])),
                        fmaxf(fmaxf(st[5][n][0], st[5][n][1]), fmaxf(st[5][n][2], st[5][n][3])));
      float tcf = fmaxf(fmaxf(fmaxf(st[6][n][0], st[6][n][1]), fmaxf(st[6][n][2], st[6][n][3])),
                        fmaxf(fmaxf(st[7][n][0], st[7][n][1]), fmaxf(st[7][n][2], st[7][n][3])));
      float vm = fmaxf(fmaxf(t03, t47), fmaxf(t8b, tcf));
      vm = fmaxf(vm, __shfl_xor(vm, 16));
      vm = fmaxf(vm, __shfl_xor(vm, 32));
      if (__any(vm > mrun[n] + THRP)) {  // defer-max with threshold
        float mnew = fmaxf(mrun[n], vm);
        float fac = exp2_fast((mrun[n] - mnew) * SCL2);
        mrun[n] = mnew;
        accL[n] *= fac;
#pragma unroll
        for (int m = 0; m < 4; ++m) accO[m][n] *= fac;
      }
      float mc = mrun[n] * SCL2;
#pragma unroll
      for (int m = 0; m < 8; ++m) {
        float p0 = exp2_fast(st[m][n][0] * SCL2 - mc);
        float p1 = exp2_fast(st[m][n][1] * SCL2 - mc);
        float p2 = exp2_fast(st[m][n][2] * SCL2 - mc);
        float p3 = exp2_fast(st[m][n][3] * SCL2 - mc);
        pdw[n][m].x = pkrtz(p0, p1);
        pdw[n][m].y = pkrtz(p2, p3);
      }
    }

    // ---- PV: P already in B-frag layout thanks to sigma ----
    f16x8 pb[2][4];
#pragma unroll
    for (int n = 0; n < 2; ++n)
#pragma unroll
      for (int ks = 0; ks < 4; ++ks) {
        union { uint4 u; f16x8 h; } c;
        c.u = make_uint4(pdw[n][2 * ks].x, pdw[n][2 * ks].y,
                         pdw[n][2 * ks + 1].x, pdw[n][2 * ks + 1].y);
        pb[n][ks] = c.h;
      }
    __builtin_amdgcn_s_setprio(1);
#pragma unroll
    for (int m = 0; m < 4; ++m)
#pragma unroll
      for (int ks = 0; ks < 4; ++ks) {
        int d = m * 16 + lr;
        int voff = (d << 8) + (ks << 6) + (lg << 4);
        voff ^= (d & 15) << 4;
        f16x8 av = *(const f16x8*)(vb + voff);
        accO[m][0] = MFMA16(av, pb[0][ks], accO[m][0]);
        accO[m][1] = MFMA16(av, pb[1][ks], accO[m][1]);
      }
#pragma unroll
    for (int ks = 0; ks < 4; ++ks) {
      accL[0] = MFMA16(ones, pb[0][ks], accL[0]);
      accL[1] = MFMA16(ones, pb[1][ks], accL[1]);
    }
    __builtin_amdgcn_s_setprio(0);
  }

  // ---- epilogue: normalize, gate (pre-sigmoided f16), write fp16 ----
#pragma unroll
  for (int n = 0; n < 2; ++n) {
    float rl = 1.0f / accL[n][0];
    int orow = qrow0 + n * 16 + lr;
#pragma unroll
    for (int m = 0; m < 4; ++m) {
      size_t idx = (size_t)orow * 1024 + h * 64 + m * 16 + lg * 4;
      f16x4 gv = *(const f16x4*)&g16[idx];
      f16x4 ov;
      ov[0] = (f16)(accO[m][n][0] * rl * (float)gv[0]);
      ov[1] = (f16)(accO[m][n][1] * rl * (float)gv[1]);
      ov[2] = (f16)(accO[m][n][2] * rl * (float)gv[2]);
      ov[3] = (f16)(accO[m][n][3] * rl * (float)gv[3]);
      *(f16x4*)&a16[idx] = ov;
    }
  }
}

// ---------------------------------------------------------------------------
extern "C" void kernel_launch(void* const* d_in, const int* in_sizes, int n_in,
                              void* d_out, int out_size, void* d_ws, size_t ws_size,
                              hipStream_t stream) {
  const float* x      = (const float*)d_in[0];
  const float* freqs  = (const float*)d_in[1];
  const float* w_qkv  = (const float*)d_in[2];
  const float* w_out  = (const float*)d_in[3];
  const float* qn_w   = (const float*)d_in[4];
  const float* qn_b   = (const float*)d_in[5];
  const float* kn_w   = (const float*)d_in[6];
  const float* kn_b   = (const float*)d_in[7];
  float* out = (float*)d_out;
  char* ws = (char*)d_ws;
  const size_t MB = 1024 * 1024;
  // ws map (~67 MB):
  f16*   v_t   = (f16*)(ws + 0);         // 8 MB  [b,h,d,s]
  f16*   x16   = (f16*)(ws + 8 * MB);    // 8 MB  (aliased by a16 after GEMM1)
  f16*   wq16  = (f16*)(ws + 16 * MB);   // 8 MB  w_qkv^T fp16
  f16*   wo16  = (f16*)(ws + 24 * MB);   // 2 MB  w_out^T fp16
  f16*   qraw  = (f16*)(ws + 26 * MB);   // 8 MB  raw q (LN fused in attn)
  f16*   kraw  = (f16*)(ws + 34 * MB);   // 8 MB  raw k (pre-LN)
  f16*   k_h   = (f16*)(ws + 50 * MB);   // 8 MB
  f16*   g16   = (f16*)(ws + 58 * MB);   // 8 MB  sigmoid(gate) f16
  float* tbl   = (float*)(ws + 66 * MB); // 0.5 MB
  f16*   a16   = x16;                    // alias: x dead after GEMM1

  if (ws_size < (size_t)67 * MB) {  // sentinel: signals ws shortfall in absmax
    fill_debug_kernel<<<(out_size + 255) / 256, 256, 0, stream>>>(out, out_size);
    return;
  }

  prep_kernel<<<3584, 256, 0, stream>>>(freqs, tbl, x, x16, w_qkv, wq16, w_out, wo16);
  gemm_qkv_256<<<dim3(16, 16), 512, 0, stream>>>(x16, wq16, 1024, qraw, kraw, g16, v_t);
  norm_k16_kernel<<<4096, 256, 0, stream>>>(kraw, tbl, kn_w, kn_b, k_h);
  attn_kernel<<<512, 256, 0, stream>>>(qraw, k_h, v_t, tbl, qn_w, qn_b, g16, a16);
  gemm_out_128x64<<<dim3(16, 32), 256, 0, stream>>>(a16, wo16, out, 4096, 1024, 1024);
}